// Round 2
// baseline (389.759 us; speedup 1.0000x reference)
//
#include <hip/hip_runtime.h>
#include <hip/hip_bf16.h>

// All reference inputs/outputs are jnp.float32 -> const float* / float*.

// wa[f*4+h] = sum_d W[f, h*128+d] * a[h*128+d]   (W is [FIN,512], a is [4,128])
__global__ void prep_wa(const float* __restrict__ W0, const float* __restrict__ a0s,
                        const float* __restrict__ a0n,
                        const float* __restrict__ W1, const float* __restrict__ a1s,
                        const float* __restrict__ a1n,
                        float* __restrict__ wa0s, float* __restrict__ wa0n,
                        float* __restrict__ wa1s, float* __restrict__ wa1n) {
  int idx = blockIdx.x * 256 + threadIdx.x;
  const float* W; const float* a; float* dst; int i;
  if (idx < 512)              { W = W0; a = a0s; dst = wa0s; i = idx; }
  else if (idx < 1024)        { W = W0; a = a0n; dst = wa0n; i = idx - 512; }
  else if (idx < 1024 + 2048) { W = W1; a = a1s; dst = wa1s; i = idx - 1024; }
  else if (idx < 1024 + 4096) { W = W1; a = a1n; dst = wa1n; i = idx - 3072; }
  else return;
  int f = i >> 2, h = i & 3;
  const float* wrow = W + (size_t)f * 512 + h * 128;
  const float* arow = a + h * 128;
  float v = 0.f;
#pragma unroll 8
  for (int d = 0; d < 128; ++d) v = fmaf(wrow[d], arow[d], v);
  dst[i] = v;
}

// One block per group g: softmax-attention over E neighbors, aggregate neighbors
// in INPUT feature space: xagg[g][h][f] = sum_e alpha[e,h] * x_neigh[g,e,f].
template <int E, int FIN>
__global__ void __launch_bounds__(256) gat_attend(
    const float* __restrict__ xself, const float* __restrict__ xneigh,
    const float* __restrict__ wa_s, const float* __restrict__ wa_n,
    float* __restrict__ xagg) {
  constexpr int STR = FIN + 1;  // +1 pad: bank-conflict-free column dots
  __shared__ float tile[(E + 1) * STR];
  __shared__ float waS[FIN * 4];
  __shared__ float waN[FIN * 4];
  __shared__ float logitS[(E + 1) * 4];
  __shared__ float alpha[E * 4];
  const int g = blockIdx.x;
  const int t = threadIdx.x;
  const float* nb = xneigh + (size_t)g * E * FIN;
  const float* sf = xself + (size_t)g * FIN;
  for (int i = t; i < E * FIN / 4; i += 256) {
    int e = (i * 4) / FIN, f = (i * 4) % FIN;
    float4 v = *reinterpret_cast<const float4*>(nb + i * 4);
    float* d = &tile[e * STR + f];
    d[0] = v.x; d[1] = v.y; d[2] = v.z; d[3] = v.w;
  }
  for (int i = t; i < FIN / 4; i += 256) {
    float4 v = *reinterpret_cast<const float4*>(sf + i * 4);
    float* d = &tile[E * STR + i * 4];
    d[0] = v.x; d[1] = v.y; d[2] = v.z; d[3] = v.w;
  }
  for (int i = t; i < FIN * 4; i += 256) { waS[i] = wa_s[i]; waN[i] = wa_n[i]; }
  __syncthreads();
  // logits: row E is the self row (uses wa_s), rows 0..E-1 neighbors (wa_n)
  if (t < (E + 1) * 4) {
    int e = t >> 2, h = t & 3;
    const float* wa = (e == E) ? waS : waN;
    const float* row = tile + e * STR;
    float v = 0.f;
#pragma unroll 8
    for (int f = 0; f < FIN; ++f) v = fmaf(row[f], wa[f * 4 + h], v);
    logitS[t] = v;
  }
  __syncthreads();
  if (t < 4) {
    const float es = logitS[E * 4 + t];
    float l[E];
    float m = -1e30f;
#pragma unroll
    for (int e = 0; e < E; ++e) {
      float x = es + logitS[e * 4 + t];
      x = (x > 0.f) ? x : 0.2f * x;  // LeakyReLU(0.2)
      l[e] = x;
      m = fmaxf(m, x);
    }
    float s = 0.f;
#pragma unroll
    for (int e = 0; e < E; ++e) {
      float p = __expf(l[e] - m);
      alpha[e * 4 + t] = p;
      s += p;
    }
    float inv = 1.f / s;
#pragma unroll
    for (int e = 0; e < E; ++e) alpha[e * 4 + t] *= inv;
  }
  __syncthreads();
  float* outg = xagg + (size_t)g * 4 * FIN;
  for (int o = t; o < 4 * FIN; o += 256) {
    int h = o / FIN, f = o - h * FIN;
    float v = 0.f;
#pragma unroll
    for (int e = 0; e < E; ++e) v = fmaf(alpha[e * 4 + h], tile[e * STR + f], v);
    outg[o] = v;
  }
}

// C[m, hb*128+n] = sum_k A[m*lda + hb*aHeadStride + k] * B[k*ldb + hb*128 + n]
// block: 64 rows x 128 cols, 256 threads, 8x4 register tile each.
__global__ void __launch_bounds__(256) gemm_tile(
    const float* __restrict__ A, int lda, int aHeadStride,
    const float* __restrict__ B, int ldb,
    float* __restrict__ C, int ldc, int K) {
  __shared__ float As[16][68];
  __shared__ float Bs[16][132];
  const int m0 = blockIdx.x * 64;
  const int hb = blockIdx.y;
  const int col0 = hb * 128;
  const float* Ab = A + (size_t)m0 * lda + (size_t)hb * aHeadStride;
  const float* Bb = B + col0;
  const int t = threadIdx.x;
  const int tn = t & 31, tm = t >> 5;
  const int lam = t >> 2, lak = (t & 3) * 4;
  const int lbk = t >> 4, lbn = (t & 15) * 8;
  float acc[8][4];
#pragma unroll
  for (int i = 0; i < 8; ++i)
#pragma unroll
    for (int j = 0; j < 4; ++j) acc[i][j] = 0.f;
  for (int k0 = 0; k0 < K; k0 += 16) {
    float4 av = *reinterpret_cast<const float4*>(Ab + (size_t)lam * lda + k0 + lak);
    As[lak + 0][lam] = av.x;
    As[lak + 1][lam] = av.y;
    As[lak + 2][lam] = av.z;
    As[lak + 3][lam] = av.w;
    const float* bp = Bb + (size_t)(k0 + lbk) * ldb + lbn;
    float4 b0 = *reinterpret_cast<const float4*>(bp);
    float4 b1 = *reinterpret_cast<const float4*>(bp + 4);
    float* bd = &Bs[lbk][lbn];
    bd[0] = b0.x; bd[1] = b0.y; bd[2] = b0.z; bd[3] = b0.w;
    bd[4] = b1.x; bd[5] = b1.y; bd[6] = b1.z; bd[7] = b1.w;
    __syncthreads();
#pragma unroll
    for (int kk = 0; kk < 16; ++kk) {
      float4 a0 = *reinterpret_cast<const float4*>(&As[kk][tm * 8]);
      float4 a1 = *reinterpret_cast<const float4*>(&As[kk][tm * 8 + 4]);
      float4 bv = *reinterpret_cast<const float4*>(&Bs[kk][tn * 4]);
      float a[8] = {a0.x, a0.y, a0.z, a0.w, a1.x, a1.y, a1.z, a1.w};
      float b[4] = {bv.x, bv.y, bv.z, bv.w};
#pragma unroll
      for (int i = 0; i < 8; ++i)
#pragma unroll
        for (int j = 0; j < 4; ++j) acc[i][j] = fmaf(a[i], b[j], acc[i][j]);
    }
    __syncthreads();
  }
#pragma unroll
  for (int i = 0; i < 8; ++i) {
    const int m = m0 + tm * 8 + i;
    float* cp = C + (size_t)m * ldc + col0 + tn * 4;
    *reinterpret_cast<float4*>(cp) =
        make_float4(acc[i][0], acc[i][1], acc[i][2], acc[i][3]);
  }
}

extern "C" void kernel_launch(void* const* d_in, const int* in_sizes, int n_in,
                              void* d_out, int out_size, void* d_ws, size_t ws_size,
                              hipStream_t stream) {
  const float* h0  = (const float*)d_in[0];
  const float* h1  = (const float*)d_in[1];
  const float* h2  = (const float*)d_in[2];
  const float* W0  = (const float*)d_in[3];
  const float* a0s = (const float*)d_in[4];
  const float* a0n = (const float*)d_in[5];
  const float* W1  = (const float*)d_in[6];
  const float* a1s = (const float*)d_in[7];
  const float* a1n = (const float*)d_in[8];
  const float* Wfc = (const float*)d_in[9];
  float* out = (float*)d_out;

  float* ws = (float*)d_ws;
  float* wa0s  = ws;                  // 512
  float* wa0n  = wa0s + 512;          // 512
  float* wa1s  = wa0n + 512;          // 2048
  float* wa1n  = wa1s + 2048;         // 2048
  float* xagg0 = wa1n + 2048;         // 1024*512   = 0.5M
  float* xagg1 = xagg0 + 1024 * 512;  // 10240*512  = 5M
  float* g0    = xagg1 + 10240 * 512; // 1024*512   = 0.5M
  float* g1    = g0 + 1024 * 512;     // 10240*512  = 5M
  float* xagg2 = xagg1;               // alias: xagg1 dead after g1 gemm (1024*2048 = 2M <= 5M)
  float* g0b   = xagg0;               // alias: xagg0 dead after g0 gemm (1024*512)
  // high-water: 5120 + 0.5M + 5M + 0.5M + 5M floats ~= 45 MB of d_ws

  prep_wa<<<20, 256, 0, stream>>>(W0, a0s, a0n, W1, a1s, a1n, wa0s, wa0n, wa1s, wa1n);
  // layer 0, level j=0: self=h0 [1024,128], neigh=h1 [1024,10,128]
  gat_attend<10, 128><<<1024, 256, 0, stream>>>(h0, h1, wa0s, wa0n, xagg0);
  // layer 0, level j=1: self=h1 [10240,128], neigh=h2 [10240,25,128]
  gat_attend<25, 128><<<10240, 256, 0, stream>>>(h1, h2, wa0s, wa0n, xagg1);
  // per-head projections with W0: g = concat_h(xagg_h @ W0[:,h-block])
  gemm_tile<<<dim3(16, 4), 256, 0, stream>>>(xagg0, 512, 128, W0, 512, g0, 512, 128);
  gemm_tile<<<dim3(160, 4), 256, 0, stream>>>(xagg1, 512, 128, W0, 512, g1, 512, 128);
  // layer 1, level j=0: self=g0 [1024,512], neigh=g1 [1024,10,512]
  gat_attend<10, 512><<<1024, 256, 0, stream>>>(g0, g1, wa1s, wa1n, xagg2);
  gemm_tile<<<dim3(16, 4), 256, 0, stream>>>(xagg2, 2048, 512, W1, 512, g0b, 512, 512);
  // final FC: out = g0b @ Wfc  [1024,512]x[512,256] -> float
  gemm_tile<<<dim3(16, 2), 256, 0, stream>>>(g0b, 512, 0, Wfc, 256, out, 256, 512);
}

// Round 3
// 356.520 us; speedup vs baseline: 1.0932x; 1.0932x over previous
//
#include <hip/hip_runtime.h>

// wa_t[h*FIN + f] = sum_d W[f, h*128+d] * a[h, d]   (transposed [h][f] layout)
__global__ void prep_wa(const float* __restrict__ W0, const float* __restrict__ a0s,
                        const float* __restrict__ a0n,
                        const float* __restrict__ W1, const float* __restrict__ a1s,
                        const float* __restrict__ a1n,
                        float* __restrict__ wa0s, float* __restrict__ wa0n,
                        float* __restrict__ wa1s, float* __restrict__ wa1n) {
  int idx = blockIdx.x * 256 + threadIdx.x;
  const float* W; const float* a; float* dst; int i; int FIN;
  if (idx < 512)       { W = W0; a = a0s; dst = wa0s; i = idx;        FIN = 128; }
  else if (idx < 1024) { W = W0; a = a0n; dst = wa0n; i = idx - 512;  FIN = 128; }
  else if (idx < 3072) { W = W1; a = a1s; dst = wa1s; i = idx - 1024; FIN = 512; }
  else if (idx < 5120) { W = W1; a = a1n; dst = wa1n; i = idx - 3072; FIN = 512; }
  else return;
  int f = i >> 2, h = i & 3;
  const float* wrow = W + (size_t)f * 512 + h * 128;
  const float* arow = a + h * 128;
  float v = 0.f;
#pragma unroll 8
  for (int d = 0; d < 128; ++d) v = fmaf(wrow[d], arow[d], v);
  dst[h * FIN + f] = v;
}

// GAT attention body: softmax over E neighbors, aggregate in input space.
// TPR lanes per row (TPR*4 == FIN), wa held in registers, logits fused into load.
template <int FIN, int MR, int TPR>
__device__ __forceinline__ void gat_body(
    const float* __restrict__ xself, const float* __restrict__ xneigh,
    const float* __restrict__ waS, const float* __restrict__ waN,
    float* __restrict__ out, int E) {
  constexpr int RPP = 256 / TPR;   // rows per pass
  constexpr int PSTR = TPR + 1;    // partial row stride (pad to break bank aliasing)
  constexpr int G = TPR / 4;       // partial groups per row
  __shared__ float tile[MR * FIN];
  __shared__ float partial[MR * PSTR];
  __shared__ float logitS[MR * 4];
  __shared__ float alpha[(MR - 1) * 4];
  const int t = threadIdx.x;
  const int el = t / TPR;
  const int f0 = (t % TPR) * 4;
  float4 wn[4], ws[4];
#pragma unroll
  for (int h = 0; h < 4; ++h) {
    wn[h] = *reinterpret_cast<const float4*>(waN + h * FIN + f0);
    ws[h] = *reinterpret_cast<const float4*>(waS + h * FIN + f0);
  }
  const int rows = E + 1;  // row E = self
  for (int p = 0; p * RPP < rows; ++p) {
    int e = p * RPP + el;
    if (e < rows) {
      const float* src = (e < E) ? (xneigh + (size_t)e * FIN + f0) : (xself + f0);
      float4 x = *reinterpret_cast<const float4*>(src);
      *reinterpret_cast<float4*>(tile + e * FIN + f0) = x;
      float ph[4];
#pragma unroll
      for (int h = 0; h < 4; ++h) {
        float4 w = (e < E) ? wn[h] : ws[h];
        ph[h] = x.x * w.x + x.y * w.y + x.z * w.z + x.w * w.w;
      }
#pragma unroll
      for (int h = 0; h < 4; ++h) {  // quad reduce (DPP)
        ph[h] += __shfl_xor(ph[h], 1);
        ph[h] += __shfl_xor(ph[h], 2);
      }
      if ((t & 3) == 0) {
        int g = (t % TPR) >> 2;
        *reinterpret_cast<float4*>(partial + e * PSTR + g * 4) =
            make_float4(ph[0], ph[1], ph[2], ph[3]);
      }
    }
  }
  __syncthreads();
  if (t < rows * 4) {
    int e = t >> 2, h = t & 3;
    float v = 0.f;
#pragma unroll
    for (int g = 0; g < G; ++g) v += partial[e * PSTR + g * 4 + h];
    logitS[t] = v;
  }
  __syncthreads();
  if (t < 4) {
    const float es = logitS[E * 4 + t];
    float m = -1e30f;
    for (int e = 0; e < E; ++e) {
      float x = es + logitS[e * 4 + t];
      x = (x > 0.f) ? x : 0.2f * x;  // LeakyReLU(0.2)
      m = fmaxf(m, x);
    }
    float s = 0.f;
    for (int e = 0; e < E; ++e) {
      float x = es + logitS[e * 4 + t];
      x = (x > 0.f) ? x : 0.2f * x;
      float p = __expf(x - m);
      alpha[e * 4 + t] = p;
      s += p;
    }
    float inv = 1.f / s;
    for (int e = 0; e < E; ++e) alpha[e * 4 + t] *= inv;
  }
  __syncthreads();
  constexpr int C = FIN / 4;
  for (int o = t; o < 4 * C; o += 256) {
    int h = o / C, f = (o % C) * 4;
    float4 acc = make_float4(0.f, 0.f, 0.f, 0.f);
#pragma unroll 5
    for (int e = 0; e < E; ++e) {
      float a = alpha[e * 4 + h];
      float4 x = *reinterpret_cast<const float4*>(tile + e * FIN + f);
      acc.x = fmaf(a, x.x, acc.x);
      acc.y = fmaf(a, x.y, acc.y);
      acc.z = fmaf(a, x.z, acc.z);
      acc.w = fmaf(a, x.w, acc.w);
    }
    *reinterpret_cast<float4*>(out + h * FIN + f) = acc;
  }
}

// Fused layer 0: blocks [0,1024) do (h0 <- h1, E=10); [1024,11264) do (h1 <- h2, E=25).
__global__ void __launch_bounds__(256) gat_layer0(
    const float* __restrict__ h0, const float* __restrict__ h1,
    const float* __restrict__ h2, const float* __restrict__ waS,
    const float* __restrict__ waN, float* __restrict__ xagg) {
  const int b = blockIdx.x;
  const float* xself;
  const float* xneigh;
  int E;
  if (b < 1024) {
    E = 10;
    xself = h0 + (size_t)b * 128;
    xneigh = h1 + (size_t)b * 10 * 128;
  } else {
    int g = b - 1024;
    E = 25;
    xself = h1 + (size_t)g * 128;
    xneigh = h2 + (size_t)g * 25 * 128;
  }
  gat_body<128, 26, 32>(xself, xneigh, waS, waN, xagg + (size_t)b * 512, E);
}

__global__ void __launch_bounds__(256) gat_layer1(
    const float* __restrict__ g0, const float* __restrict__ g1,
    const float* __restrict__ waS, const float* __restrict__ waN,
    float* __restrict__ xagg) {
  const int b = blockIdx.x;
  gat_body<512, 11, 128>(g0 + (size_t)b * 512, g1 + (size_t)b * 10 * 512,
                         waS, waN, xagg + (size_t)b * 2048, 10);
}

// C[m, hb*128+n] = sum_k A[m*lda + hb*aHeadStride + k] * B[k*ldb + hb*128 + n]
__global__ void __launch_bounds__(256) gemm_tile(
    const float* __restrict__ A, int lda, int aHeadStride,
    const float* __restrict__ B, int ldb,
    float* __restrict__ C, int ldc, int K) {
  __shared__ float As[16][68];
  __shared__ float Bs[16][132];
  const int m0 = blockIdx.x * 64;
  const int hb = blockIdx.y;
  const int col0 = hb * 128;
  const float* Ab = A + (size_t)m0 * lda + (size_t)hb * aHeadStride;
  const float* Bb = B + col0;
  const int t = threadIdx.x;
  const int tn = t & 31, tm = t >> 5;
  const int lam = t >> 2, lak = (t & 3) * 4;
  const int lbk = t >> 4, lbn = (t & 15) * 8;
  float acc[8][4];
#pragma unroll
  for (int i = 0; i < 8; ++i)
#pragma unroll
    for (int j = 0; j < 4; ++j) acc[i][j] = 0.f;
  for (int k0 = 0; k0 < K; k0 += 16) {
    float4 av = *reinterpret_cast<const float4*>(Ab + (size_t)lam * lda + k0 + lak);
    As[lak + 0][lam] = av.x;
    As[lak + 1][lam] = av.y;
    As[lak + 2][lam] = av.z;
    As[lak + 3][lam] = av.w;
    const float* bp = Bb + (size_t)(k0 + lbk) * ldb + lbn;
    float4 b0 = *reinterpret_cast<const float4*>(bp);
    float4 b1 = *reinterpret_cast<const float4*>(bp + 4);
    float* bd = &Bs[lbk][lbn];
    bd[0] = b0.x; bd[1] = b0.y; bd[2] = b0.z; bd[3] = b0.w;
    bd[4] = b1.x; bd[5] = b1.y; bd[6] = b1.z; bd[7] = b1.w;
    __syncthreads();
#pragma unroll
    for (int kk = 0; kk < 16; ++kk) {
      float4 a0 = *reinterpret_cast<const float4*>(&As[kk][tm * 8]);
      float4 a1 = *reinterpret_cast<const float4*>(&As[kk][tm * 8 + 4]);
      float4 bv = *reinterpret_cast<const float4*>(&Bs[kk][tn * 4]);
      float a[8] = {a0.x, a0.y, a0.z, a0.w, a1.x, a1.y, a1.z, a1.w};
      float b[4] = {bv.x, bv.y, bv.z, bv.w};
#pragma unroll
      for (int i = 0; i < 8; ++i)
#pragma unroll
        for (int j = 0; j < 4; ++j) acc[i][j] = fmaf(a[i], b[j], acc[i][j]);
    }
    __syncthreads();
  }
#pragma unroll
  for (int i = 0; i < 8; ++i) {
    const int m = m0 + tm * 8 + i;
    float* cp = C + (size_t)m * ldc + col0 + tn * 4;
    *reinterpret_cast<float4*>(cp) =
        make_float4(acc[i][0], acc[i][1], acc[i][2], acc[i][3]);
  }
}

extern "C" void kernel_launch(void* const* d_in, const int* in_sizes, int n_in,
                              void* d_out, int out_size, void* d_ws, size_t ws_size,
                              hipStream_t stream) {
  const float* h0  = (const float*)d_in[0];
  const float* h1  = (const float*)d_in[1];
  const float* h2  = (const float*)d_in[2];
  const float* W0  = (const float*)d_in[3];
  const float* a0s = (const float*)d_in[4];
  const float* a0n = (const float*)d_in[5];
  const float* W1  = (const float*)d_in[6];
  const float* a1s = (const float*)d_in[7];
  const float* a1n = (const float*)d_in[8];
  const float* Wfc = (const float*)d_in[9];
  float* out = (float*)d_out;

  float* ws = (float*)d_ws;
  float* wa0s  = ws;                   // [4][128]
  float* wa0n  = wa0s + 512;           // [4][128]
  float* wa1s  = wa0n + 512;           // [4][512]
  float* wa1n  = wa1s + 2048;          // [4][512]
  float* xaggA = wa1n + 2048;          // [11264][512] = 5.77M floats
  float* gcat  = xaggA + 11264 * 512;  // [11264][512] = 5.77M floats
  float* xagg2 = xaggA;                // alias: xaggA dead after gemm0 ([1024][2048] = 2.1M)
  float* g0b   = xaggA + 1024 * 2048;  // alias tail of xaggA region ([1024][512])
  // high-water ~46.2 MB of d_ws

  prep_wa<<<20, 256, 0, stream>>>(W0, a0s, a0n, W1, a1s, a1n, wa0s, wa0n, wa1s, wa1n);
  // layer 0 (both levels fused): xaggA rows 0..1023 = level0, 1024..11263 = level1
  gat_layer0<<<11264, 256, 0, stream>>>(h0, h1, h2, wa0s, wa0n, xaggA);
  // per-head projection with W0 for all 11264 groups at once
  gemm_tile<<<dim3(176, 4), 256, 0, stream>>>(xaggA, 512, 128, W0, 512, gcat, 512, 128);
  // layer 1: self = gcat[0..1023], neigh = gcat[1024..11263] as [1024][10][512]
  gat_layer1<<<1024, 256, 0, stream>>>(gcat, gcat + (size_t)1024 * 512, wa1s, wa1n, xagg2);
  gemm_tile<<<dim3(16, 4), 256, 0, stream>>>(xagg2, 2048, 512, W1, 512, g0b, 512, 512);
  // final FC: out = g0b @ Wfc  [1024,512]x[512,256]
  gemm_tile<<<dim3(16, 2), 256, 0, stream>>>(g0b, 512, 0, Wfc, 256, out, 256, 512);
}

// Round 4
// 297.820 us; speedup vs baseline: 1.3087x; 1.1971x over previous
//
#include <hip/hip_runtime.h>

// ---------------- P1: wa vectors + T[h] = W1[:, hblk] @ Wfc[hblk, :] ----------------
// wa layout: wa[h*FIN + f] = sum_d W[f, h*128+d] * a[h, d]
// T layout:  T[h*512*256 + k*256 + o] = sum_m W1[k, h*128+m] * Wfc[h*128+m, o]
__global__ void __launch_bounds__(256) prep1(
    const float* __restrict__ W0, const float* __restrict__ a0s,
    const float* __restrict__ a0n,
    const float* __restrict__ W1, const float* __restrict__ a1s,
    const float* __restrict__ a1n, const float* __restrict__ Wfc,
    float* __restrict__ wa0s, float* __restrict__ wa0n,
    float* __restrict__ wa1s, float* __restrict__ wa1n,
    float* __restrict__ T) {
  int idx = blockIdx.x * 256 + threadIdx.x;
  if (idx < 5120) {
    const float* W; const float* a; float* dst; int i; int FIN;
    if (idx < 512)       { W = W0; a = a0s; dst = wa0s; i = idx;        FIN = 128; }
    else if (idx < 1024) { W = W0; a = a0n; dst = wa0n; i = idx - 512;  FIN = 128; }
    else if (idx < 3072) { W = W1; a = a1s; dst = wa1s; i = idx - 1024; FIN = 512; }
    else                 { W = W1; a = a1n; dst = wa1n; i = idx - 3072; FIN = 512; }
    int f = i >> 2, h = i & 3;
    const float* wrow = W + (size_t)f * 512 + h * 128;
    const float* arow = a + h * 128;
    float v = 0.f;
#pragma unroll 8
    for (int d = 0; d < 128; ++d) v = fmaf(wrow[d], arow[d], v);
    dst[h * FIN + f] = v;
    return;
  }
  int j = idx - 5120;
  if (j >= 4 * 512 * 256) return;
  int h = j >> 17;
  int k = (j >> 8) & 511;
  int o = j & 255;
  const float* w1row = W1 + (size_t)k * 512 + h * 128;
  const float* fcol = Wfc + (size_t)h * 128 * 256 + o;
  float v = 0.f;
#pragma unroll 8
  for (int m = 0; m < 128; ++m) v = fmaf(w1row[m], fcol[(size_t)m * 256], v);
  T[j] = v;
}

// ---------------- P2: va vectors + Wfinal[h][(h0,f)][o] ----------------
// va[h*512 + h0*128 + f] = sum_n W0[f, h0*128+n] * wa1[h*512 + h0*128+n]
// Wfinal[h*512*256 + (h0*128+f)*256 + o] = sum_n W0[f, h0*128+n] * T[h][h0*128+n][o]
__global__ void __launch_bounds__(256) prep2(
    const float* __restrict__ W0, const float* __restrict__ wa1s,
    const float* __restrict__ wa1n, const float* __restrict__ T,
    float* __restrict__ va1s, float* __restrict__ va1n,
    float* __restrict__ Wfinal) {
  int idx = blockIdx.x * 256 + threadIdx.x;
  if (idx < 4096) {
    const float* wa = (idx < 2048) ? wa1s : wa1n;
    float* dst = (idx < 2048) ? va1s : va1n;
    int i = idx & 2047;
    int h = i >> 9, h0 = (i >> 7) & 3, f = i & 127;
    const float* w0row = W0 + (size_t)f * 512 + h0 * 128;
    const float* warow = wa + h * 512 + h0 * 128;
    float v = 0.f;
#pragma unroll 8
    for (int n = 0; n < 128; ++n) v = fmaf(w0row[n], warow[n], v);
    dst[i] = v;
    return;
  }
  int j = idx - 4096;
  if (j >= 4 * 512 * 256) return;
  int h = j >> 17;
  int kk = (j >> 8) & 511;  // (h0,f)
  int o = j & 255;
  int h0 = kk >> 7, f = kk & 127;
  const float* w0row = W0 + (size_t)f * 512 + h0 * 128;
  const float* tcol = T + (size_t)h * 512 * 256 + (size_t)(h0 * 128) * 256 + o;
  float v = 0.f;
#pragma unroll 8
  for (int n = 0; n < 128; ++n) v = fmaf(w0row[n], tcol[(size_t)n * 256], v);
  Wfinal[j] = v;
}

// ---------------- GAT attention body (softmax over E, aggregate in input space) ----
template <int FIN, int MR, int TPR>
__device__ __forceinline__ void gat_body(
    const float* __restrict__ xself, const float* __restrict__ xneigh,
    const float* __restrict__ waS, const float* __restrict__ waN,
    float* __restrict__ out, int E) {
  constexpr int RPP = 256 / TPR;
  constexpr int PSTR = TPR + 1;
  constexpr int G = TPR / 4;
  __shared__ float tile[MR * FIN];
  __shared__ float partial[MR * PSTR];
  __shared__ float logitS[MR * 4];
  __shared__ float alpha[(MR - 1) * 4];
  const int t = threadIdx.x;
  const int el = t / TPR;
  const int f0 = (t % TPR) * 4;
  float4 wn[4], ws[4];
#pragma unroll
  for (int h = 0; h < 4; ++h) {
    wn[h] = *reinterpret_cast<const float4*>(waN + h * FIN + f0);
    ws[h] = *reinterpret_cast<const float4*>(waS + h * FIN + f0);
  }
  const int rows = E + 1;  // row E = self
  for (int p = 0; p * RPP < rows; ++p) {
    int e = p * RPP + el;
    if (e < rows) {
      const float* src = (e < E) ? (xneigh + (size_t)e * FIN + f0) : (xself + f0);
      float4 x = *reinterpret_cast<const float4*>(src);
      *reinterpret_cast<float4*>(tile + e * FIN + f0) = x;
      float ph[4];
#pragma unroll
      for (int h = 0; h < 4; ++h) {
        float4 w = (e < E) ? wn[h] : ws[h];
        ph[h] = x.x * w.x + x.y * w.y + x.z * w.z + x.w * w.w;
      }
#pragma unroll
      for (int h = 0; h < 4; ++h) {
        ph[h] += __shfl_xor(ph[h], 1);
        ph[h] += __shfl_xor(ph[h], 2);
      }
      if ((t & 3) == 0) {
        int g = (t % TPR) >> 2;
        *reinterpret_cast<float4*>(partial + e * PSTR + g * 4) =
            make_float4(ph[0], ph[1], ph[2], ph[3]);
      }
    }
  }
  __syncthreads();
  if (t < rows * 4) {
    int e = t >> 2, h = t & 3;
    float v = 0.f;
#pragma unroll
    for (int g = 0; g < G; ++g) v += partial[e * PSTR + g * 4 + h];
    logitS[t] = v;
  }
  __syncthreads();
  if (t < 4) {
    const float es = logitS[E * 4 + t];
    float m = -1e30f;
    for (int e = 0; e < E; ++e) {
      float x = es + logitS[e * 4 + t];
      x = (x > 0.f) ? x : 0.2f * x;  // LeakyReLU(0.2)
      m = fmaxf(m, x);
    }
    float s = 0.f;
    for (int e = 0; e < E; ++e) {
      float x = es + logitS[e * 4 + t];
      x = (x > 0.f) ? x : 0.2f * x;
      float p = __expf(x - m);
      alpha[e * 4 + t] = p;
      s += p;
    }
    float inv = 1.f / s;
    for (int e = 0; e < E; ++e) alpha[e * 4 + t] *= inv;
  }
  __syncthreads();
  constexpr int C = FIN / 4;
  for (int o = t; o < 4 * C; o += 256) {
    int h = o / C, f = (o % C) * 4;
    float4 acc = make_float4(0.f, 0.f, 0.f, 0.f);
#pragma unroll 5
    for (int e = 0; e < E; ++e) {
      float a = alpha[e * 4 + h];
      float4 x = *reinterpret_cast<const float4*>(tile + e * FIN + f);
      acc.x = fmaf(a, x.x, acc.x);
      acc.y = fmaf(a, x.y, acc.y);
      acc.z = fmaf(a, x.z, acc.z);
      acc.w = fmaf(a, x.w, acc.w);
    }
    *reinterpret_cast<float4*>(out + h * FIN + f) = acc;
  }
}

// Layer 0 fused: blocks [0,1024): (h0 <- h1, E=10); [1024,11264): (h1 <- h2, E=25).
__global__ void __launch_bounds__(256) gat_layer0(
    const float* __restrict__ h0, const float* __restrict__ h1,
    const float* __restrict__ h2, const float* __restrict__ waS,
    const float* __restrict__ waN, float* __restrict__ xagg) {
  const int b = blockIdx.x;
  const float* xself;
  const float* xneigh;
  int E;
  if (b < 1024) {
    E = 10;
    xself = h0 + (size_t)b * 128;
    xneigh = h1 + (size_t)b * 10 * 128;
  } else {
    int g = b - 1024;
    E = 25;
    xself = h1 + (size_t)g * 128;
    xneigh = h2 + (size_t)g * 25 * 128;
  }
  gat_body<128, 26, 32>(xself, xneigh, waS, waN, xagg + (size_t)b * 512, E);
}

// Layer 1 directly on xagg (va-composited logits): aggx[b][h1][(h0,f)].
__global__ void __launch_bounds__(256) gat_layer1(
    const float* __restrict__ xagg0, const float* __restrict__ xagg1,
    const float* __restrict__ vaS, const float* __restrict__ vaN,
    float* __restrict__ aggx) {
  const int b = blockIdx.x;
  gat_body<512, 11, 128>(xagg0 + (size_t)b * 512, xagg1 + (size_t)b * 10 * 512,
                         vaS, vaN, aggx + (size_t)b * 2048, 10);
}

// K-split GEMM: C_part[ks][m, hb*128+n] = sum_{k in chunk} A[m,k]*B[k, hb*128+n]
__global__ void __launch_bounds__(256) gemm_ksplit(
    const float* __restrict__ A, int lda,
    const float* __restrict__ B, int ldb,
    float* __restrict__ Cpart, int ldc, int Kchunk) {
  __shared__ float As[16][68];
  __shared__ float Bs[16][132];
  const int m0 = blockIdx.x * 64;
  const int hb = blockIdx.y;
  const int ks = blockIdx.z;
  const int col0 = hb * 128;
  const float* Ab = A + (size_t)m0 * lda + (size_t)ks * Kchunk;
  const float* Bb = B + (size_t)ks * Kchunk * ldb + col0;
  float* Cb = Cpart + (size_t)ks * 1024 * 256;
  const int t = threadIdx.x;
  const int tn = t & 31, tm = t >> 5;
  const int lam = t >> 2, lak = (t & 3) * 4;
  const int lbk = t >> 4, lbn = (t & 15) * 8;
  float acc[8][4];
#pragma unroll
  for (int i = 0; i < 8; ++i)
#pragma unroll
    for (int j = 0; j < 4; ++j) acc[i][j] = 0.f;
  for (int k0 = 0; k0 < Kchunk; k0 += 16) {
    float4 av = *reinterpret_cast<const float4*>(Ab + (size_t)lam * lda + k0 + lak);
    As[lak + 0][lam] = av.x;
    As[lak + 1][lam] = av.y;
    As[lak + 2][lam] = av.z;
    As[lak + 3][lam] = av.w;
    const float* bp = Bb + (size_t)(k0 + lbk) * ldb + lbn;
    float4 b0 = *reinterpret_cast<const float4*>(bp);
    float4 b1 = *reinterpret_cast<const float4*>(bp + 4);
    float* bd = &Bs[lbk][lbn];
    bd[0] = b0.x; bd[1] = b0.y; bd[2] = b0.z; bd[3] = b0.w;
    bd[4] = b1.x; bd[5] = b1.y; bd[6] = b1.z; bd[7] = b1.w;
    __syncthreads();
#pragma unroll
    for (int kk = 0; kk < 16; ++kk) {
      float4 a0 = *reinterpret_cast<const float4*>(&As[kk][tm * 8]);
      float4 a1 = *reinterpret_cast<const float4*>(&As[kk][tm * 8 + 4]);
      float4 bv = *reinterpret_cast<const float4*>(&Bs[kk][tn * 4]);
      float a[8] = {a0.x, a0.y, a0.z, a0.w, a1.x, a1.y, a1.z, a1.w};
      float b[4] = {bv.x, bv.y, bv.z, bv.w};
#pragma unroll
      for (int i = 0; i < 8; ++i)
#pragma unroll
        for (int j = 0; j < 4; ++j) acc[i][j] = fmaf(a[i], b[j], acc[i][j]);
    }
    __syncthreads();
  }
#pragma unroll
  for (int i = 0; i < 8; ++i) {
    const int m = m0 + tm * 8 + i;
    float* cp = Cb + (size_t)m * ldc + col0 + tn * 4;
    *reinterpret_cast<float4*>(cp) =
        make_float4(acc[i][0], acc[i][1], acc[i][2], acc[i][3]);
  }
}

// out[i] = sum_{ks<8} Cpart[ks][i]  (float4-vectorized)
__global__ void __launch_bounds__(256) reduce8(
    const float* __restrict__ Cpart, float* __restrict__ out) {
  int i = blockIdx.x * 256 + threadIdx.x;  // float4 index, 65536 total
  const float4* p = reinterpret_cast<const float4*>(Cpart) + i;
  float4 s = p[0];
#pragma unroll
  for (int ks = 1; ks < 8; ++ks) {
    float4 v = p[(size_t)ks * 65536];
    s.x += v.x; s.y += v.y; s.z += v.z; s.w += v.w;
  }
  reinterpret_cast<float4*>(out)[i] = s;
}

extern "C" void kernel_launch(void* const* d_in, const int* in_sizes, int n_in,
                              void* d_out, int out_size, void* d_ws, size_t ws_size,
                              hipStream_t stream) {
  const float* h0  = (const float*)d_in[0];
  const float* h1  = (const float*)d_in[1];
  const float* h2  = (const float*)d_in[2];
  const float* W0  = (const float*)d_in[3];
  const float* a0s = (const float*)d_in[4];
  const float* a0n = (const float*)d_in[5];
  const float* W1  = (const float*)d_in[6];
  const float* a1s = (const float*)d_in[7];
  const float* a1n = (const float*)d_in[8];
  const float* Wfc = (const float*)d_in[9];
  float* out = (float*)d_out;

  float* ws = (float*)d_ws;
  float* wa0s   = ws;                    // [4][128]
  float* wa0n   = wa0s + 512;            // [4][128]
  float* wa1s   = wa0n + 512;            // [4][512]
  float* wa1n   = wa1s + 2048;           // [4][512]
  float* va1s   = wa1n + 2048;           // [4][4][128]
  float* va1n   = va1s + 2048;           // [4][4][128]
  float* T      = va1n + 2048;           // [4][512][256] = 524288
  float* Wfinal = T + 524288;            // [4][512][256] = 524288
  float* xaggA  = Wfinal + 524288;       // [11264][512]  = 5767168
  float* aggx   = xaggA + 11264 * 512;   // [1024][2048]  = 2097152
  float* Cpart  = aggx + 2097152;        // [8][1024][256]= 2097152
  // total ~11.0M floats = 44.1 MB

  // P1: wa vectors + T
  prep1<<<2068, 256, 0, stream>>>(W0, a0s, a0n, W1, a1s, a1n, Wfc,
                                  wa0s, wa0n, wa1s, wa1n, T);
  // P2: va vectors + Wfinal
  prep2<<<2064, 256, 0, stream>>>(W0, wa1s, wa1n, T, va1s, va1n, Wfinal);
  // Layer 0 (both levels): xaggA rows 0..1023 = level0, 1024..11263 = level1
  gat_layer0<<<11264, 256, 0, stream>>>(h0, h1, h2, wa0s, wa0n, xaggA);
  // Layer 1 directly in xagg space
  gat_layer1<<<1024, 256, 0, stream>>>(xaggA, xaggA + (size_t)1024 * 512,
                                       va1s, va1n, aggx);
  // Final: out = aggx[1024,2048] @ Wfinal[2048,256], K-split x8 + reduce
  gemm_ksplit<<<dim3(16, 2, 8), 256, 0, stream>>>(aggx, 2048, Wfinal, 256,
                                                  Cpart, 256, 256);
  reduce8<<<256, 256, 0, stream>>>(Cpart, out);
}

// Round 5
// 268.900 us; speedup vs baseline: 1.4495x; 1.1075x over previous
//
#include <hip/hip_runtime.h>

// ======================= shared-scratch tiled GEMM body =======================
// C[m0+m, col0+n] = sum_k A[(m0+m)*lda + k] * B[k*ldb + col0 + n]
// 64 rows x 128 cols per block, 256 threads, 8x4 register tile.
// smem needs 16*68 + 16*132 = 3200 floats.
__device__ __forceinline__ void gemm_body(
    float* __restrict__ smem,
    const float* __restrict__ A, int lda,
    const float* __restrict__ B, int ldb,
    float* __restrict__ C, int ldc, int K,
    int m0, int col0) {
  float* As = smem;            // [16][68]
  float* Bs = smem + 16 * 68;  // [16][132]
  const int t = threadIdx.x;
  const int tn = t & 31, tm = t >> 5;
  const int lam = t >> 2, lak = (t & 3) * 4;
  const int lbk = t >> 4, lbn = (t & 15) * 8;
  float acc[8][4];
#pragma unroll
  for (int i = 0; i < 8; ++i)
#pragma unroll
    for (int j = 0; j < 4; ++j) acc[i][j] = 0.f;
  for (int k0 = 0; k0 < K; k0 += 16) {
    float4 av = *reinterpret_cast<const float4*>(A + (size_t)(m0 + lam) * lda + k0 + lak);
    As[(lak + 0) * 68 + lam] = av.x;
    As[(lak + 1) * 68 + lam] = av.y;
    As[(lak + 2) * 68 + lam] = av.z;
    As[(lak + 3) * 68 + lam] = av.w;
    const float* bp = B + (size_t)(k0 + lbk) * ldb + col0 + lbn;
    float4 b0 = *reinterpret_cast<const float4*>(bp);
    float4 b1 = *reinterpret_cast<const float4*>(bp + 4);
    float* bd = &Bs[lbk * 132 + lbn];
    bd[0] = b0.x; bd[1] = b0.y; bd[2] = b0.z; bd[3] = b0.w;
    bd[4] = b1.x; bd[5] = b1.y; bd[6] = b1.z; bd[7] = b1.w;
    __syncthreads();
#pragma unroll
    for (int kk = 0; kk < 16; ++kk) {
      float4 a0 = *reinterpret_cast<const float4*>(&As[kk * 68 + tm * 8]);
      float4 a1 = *reinterpret_cast<const float4*>(&As[kk * 68 + tm * 8 + 4]);
      float4 bv = *reinterpret_cast<const float4*>(&Bs[kk * 132 + tn * 4]);
      float a[8] = {a0.x, a0.y, a0.z, a0.w, a1.x, a1.y, a1.z, a1.w};
      float b[4] = {bv.x, bv.y, bv.z, bv.w};
#pragma unroll
      for (int i = 0; i < 8; ++i)
#pragma unroll
        for (int j = 0; j < 4; ++j) acc[i][j] = fmaf(a[i], b[j], acc[i][j]);
    }
    __syncthreads();
  }
#pragma unroll
  for (int i = 0; i < 8; ++i) {
    float* cp = C + (size_t)(m0 + tm * 8 + i) * ldc + col0 + tn * 4;
    *reinterpret_cast<float4*>(cp) =
        make_float4(acc[i][0], acc[i][1], acc[i][2], acc[i][3]);
  }
}

// ======================= GAT attention body (compile-time E) ==================
// softmax over E neighbors, aggregate in input space; wa in registers.
// smem floats needed: (E+1)*FIN + (E+1)*(TPR+1) + (E+1)*4 + E*4.
template <int FIN, int TPR, int E>
__device__ __forceinline__ void gat_body(
    float* __restrict__ smem,
    const float* __restrict__ xself, const float* __restrict__ xneigh,
    const float* __restrict__ waS, const float* __restrict__ waN,
    float* __restrict__ out) {
  constexpr int MR = E + 1;
  constexpr int RPP = 256 / TPR;
  constexpr int PSTR = TPR + 1;
  constexpr int G = TPR / 4;
  float* tile = smem;                   // MR*FIN
  float* partial = tile + MR * FIN;     // MR*PSTR
  float* logitS = partial + MR * PSTR;  // MR*4
  float* alpha = logitS + MR * 4;       // E*4
  const int t = threadIdx.x;
  const int el = t / TPR;
  const int f0 = (t % TPR) * 4;
  float4 wn[4], ws[4];
#pragma unroll
  for (int h = 0; h < 4; ++h) {
    wn[h] = *reinterpret_cast<const float4*>(waN + h * FIN + f0);
    ws[h] = *reinterpret_cast<const float4*>(waS + h * FIN + f0);
  }
#pragma unroll
  for (int p = 0; p * RPP < MR; ++p) {
    int e = p * RPP + el;
    if (e < MR) {
      const float* src = (e < E) ? (xneigh + (size_t)e * FIN + f0) : (xself + f0);
      float4 x = *reinterpret_cast<const float4*>(src);
      *reinterpret_cast<float4*>(tile + e * FIN + f0) = x;
      float ph[4];
#pragma unroll
      for (int h = 0; h < 4; ++h) {
        float4 w = (e < E) ? wn[h] : ws[h];
        ph[h] = x.x * w.x + x.y * w.y + x.z * w.z + x.w * w.w;
      }
#pragma unroll
      for (int h = 0; h < 4; ++h) {  // quad reduce (DPP)
        ph[h] += __shfl_xor(ph[h], 1);
        ph[h] += __shfl_xor(ph[h], 2);
      }
      if ((t & 3) == 0) {
        int g = (t % TPR) >> 2;
        *reinterpret_cast<float4*>(partial + e * PSTR + g * 4) =
            make_float4(ph[0], ph[1], ph[2], ph[3]);
      }
    }
  }
  __syncthreads();
  if (t < MR * 4) {
    int e = t >> 2, h = t & 3;
    float v = 0.f;
#pragma unroll
    for (int g = 0; g < G; ++g) v += partial[e * PSTR + g * 4 + h];
    logitS[t] = v;
  }
  __syncthreads();
  if (t < 4) {
    const float es = logitS[E * 4 + t];
    float m = -1e30f;
#pragma unroll
    for (int e = 0; e < E; ++e) {
      float x = es + logitS[e * 4 + t];
      x = (x > 0.f) ? x : 0.2f * x;  // LeakyReLU(0.2)
      m = fmaxf(m, x);
    }
    float s = 0.f;
#pragma unroll
    for (int e = 0; e < E; ++e) {
      float x = es + logitS[e * 4 + t];
      x = (x > 0.f) ? x : 0.2f * x;
      float p = __expf(x - m);
      alpha[e * 4 + t] = p;
      s += p;
    }
    float inv = 1.f / s;
#pragma unroll
    for (int e = 0; e < E; ++e) alpha[e * 4 + t] *= inv;
  }
  __syncthreads();
  constexpr int C = FIN / 4;
  for (int o = t; o < 4 * C; o += 256) {
    int h = o / C, f = (o % C) * 4;
    float4 acc = make_float4(0.f, 0.f, 0.f, 0.f);
#pragma unroll
    for (int e = 0; e < E; ++e) {
      float a = alpha[e * 4 + h];
      float4 x = *reinterpret_cast<const float4*>(tile + e * FIN + f);
      acc.x = fmaf(a, x.x, acc.x);
      acc.y = fmaf(a, x.y, acc.y);
      acc.z = fmaf(a, x.z, acc.z);
      acc.w = fmaf(a, x.w, acc.w);
    }
    *reinterpret_cast<float4*>(out + h * FIN + f) = acc;
  }
}

// ======================= prepA: wa vectors + T = W1_hblk @ Wfc_hblk ===========
// blocks [0,64): T gemm (4 heads x 8 mb x 2 nb); blocks [64,84): wa naive.
__global__ void __launch_bounds__(256) prepA(
    const float* __restrict__ W0, const float* __restrict__ a0s,
    const float* __restrict__ a0n,
    const float* __restrict__ W1, const float* __restrict__ a1s,
    const float* __restrict__ a1n, const float* __restrict__ Wfc,
    float* __restrict__ wa0s, float* __restrict__ wa0n,
    float* __restrict__ wa1s, float* __restrict__ wa1n,
    float* __restrict__ T) {
  __shared__ float smem[3200];
  const int b = blockIdx.x;
  if (b < 64) {
    // T[h][k][o] = sum_m W1[k, h*128+m] * Wfc[h*128+m, o]; M=512,K=128,N=256
    int h = b >> 4, mb = (b >> 1) & 7, nb = b & 1;
    gemm_body(smem, W1 + h * 128, 512, Wfc + (size_t)h * 32768, 256,
              T + (size_t)h * 131072, 256, 128, mb * 64, nb * 128);
    return;
  }
  int idx = (b - 64) * 256 + threadIdx.x;
  if (idx >= 5120) return;
  const float* W; const float* a; float* dst; int i; int FIN;
  if (idx < 512)       { W = W0; a = a0s; dst = wa0s; i = idx;        FIN = 128; }
  else if (idx < 1024) { W = W0; a = a0n; dst = wa0n; i = idx - 512;  FIN = 128; }
  else if (idx < 3072) { W = W1; a = a1s; dst = wa1s; i = idx - 1024; FIN = 512; }
  else                 { W = W1; a = a1n; dst = wa1n; i = idx - 3072; FIN = 512; }
  int f = i >> 2, h = i & 3;
  const float* wrow = W + (size_t)f * 512 + h * 128;
  const float* arow = a + h * 128;
  float v = 0.f;
#pragma unroll 8
  for (int d = 0; d < 128; ++d) v = fmaf(wrow[d], arow[d], v);
  dst[h * FIN + f] = v;
}

// ======= fusedB: layer-0 attention (11264) + Wfinal gemm (64) + va (16) =======
__global__ void __launch_bounds__(256) fusedB(
    const float* __restrict__ h0, const float* __restrict__ h1,
    const float* __restrict__ h2, const float* __restrict__ wa0s,
    const float* __restrict__ wa0n, float* __restrict__ xagg,
    const float* __restrict__ W0, const float* __restrict__ wa1s,
    const float* __restrict__ wa1n, const float* __restrict__ T,
    float* __restrict__ va1s, float* __restrict__ va1n,
    float* __restrict__ Wfinal) {
  __shared__ float smem[4390];  // max(attn E=25: 4390, gemm: 3200)
  const int b = blockIdx.x;
  if (b < 1024) {
    gat_body<128, 32, 10>(smem, h0 + (size_t)b * 128, h1 + (size_t)b * 1280,
                          wa0s, wa0n, xagg + (size_t)b * 512);
    return;
  }
  if (b < 11264) {
    int g = b - 1024;
    gat_body<128, 32, 25>(smem, h1 + (size_t)g * 128, h2 + (size_t)g * 3200,
                          wa0s, wa0n, xagg + (size_t)b * 512);
    return;
  }
  if (b < 11264 + 64) {
    // Wfinal[h][(h0b*128+f)][o] = sum_n W0[f, h0b*128+n] * T[h][h0b*128+n][o]
    int g = b - 11264;
    int pair = g >> 2, mb = (g >> 1) & 1, nb = g & 1;
    int h = pair >> 2, h0b = pair & 3;
    gemm_body(smem, W0 + h0b * 128, 512,
              T + (size_t)h * 131072 + (size_t)h0b * 32768, 256,
              Wfinal + (size_t)h * 131072 + (size_t)h0b * 32768, 256, 128,
              mb * 64, nb * 128);
    return;
  }
  // va1: va[h*512 + h0b*128 + f] = sum_n W0[f, h0b*128+n] * wa1[h*512+h0b*128+n]
  int idx = (b - 11328) * 256 + threadIdx.x;
  if (idx >= 4096) return;
  const float* wa = (idx < 2048) ? wa1s : wa1n;
  float* dst = (idx < 2048) ? va1s : va1n;
  int i = idx & 2047;
  int h = i >> 9, h0b = (i >> 7) & 3, f = i & 127;
  const float* w0row = W0 + (size_t)f * 512 + h0b * 128;
  const float* warow = wa + h * 512 + h0b * 128;
  float v = 0.f;
#pragma unroll 8
  for (int n = 0; n < 128; ++n) v = fmaf(w0row[n], warow[n], v);
  dst[i] = v;
}

// ======================= layer 1 on xagg space ================================
__global__ void __launch_bounds__(256) gat_layer1(
    const float* __restrict__ xagg, const float* __restrict__ vaS,
    const float* __restrict__ vaN, float* __restrict__ aggx) {
  __shared__ float smem[7135];  // 11*512 + 11*129 + 44 + 40
  const int b = blockIdx.x;
  gat_body<512, 128, 10>(smem, xagg + (size_t)b * 512,
                         xagg + (size_t)(1024 + b * 10) * 512, vaS, vaN,
                         aggx + (size_t)b * 2048);
}

// ======================= tail: K-split GEMM + reduce ==========================
__global__ void __launch_bounds__(256) gemm_ksplit(
    const float* __restrict__ A, const float* __restrict__ B,
    float* __restrict__ Cpart) {
  __shared__ float smem[3200];
  const int ks = blockIdx.z;
  gemm_body(smem, A + ks * 256, 2048, B + (size_t)ks * 65536, 256,
            Cpart + (size_t)ks * 262144, 256, 256, blockIdx.x * 64,
            blockIdx.y * 128);
}

__global__ void __launch_bounds__(256) reduce8(
    const float* __restrict__ Cpart, float* __restrict__ out) {
  int i = blockIdx.x * 256 + threadIdx.x;  // float4 index, 65536 total
  const float4* p = reinterpret_cast<const float4*>(Cpart) + i;
  float4 s = p[0];
#pragma unroll
  for (int ks = 1; ks < 8; ++ks) {
    float4 v = p[(size_t)ks * 65536];
    s.x += v.x; s.y += v.y; s.z += v.z; s.w += v.w;
  }
  reinterpret_cast<float4*>(out)[i] = s;
}

extern "C" void kernel_launch(void* const* d_in, const int* in_sizes, int n_in,
                              void* d_out, int out_size, void* d_ws, size_t ws_size,
                              hipStream_t stream) {
  const float* h0  = (const float*)d_in[0];
  const float* h1  = (const float*)d_in[1];
  const float* h2  = (const float*)d_in[2];
  const float* W0  = (const float*)d_in[3];
  const float* a0s = (const float*)d_in[4];
  const float* a0n = (const float*)d_in[5];
  const float* W1  = (const float*)d_in[6];
  const float* a1s = (const float*)d_in[7];
  const float* a1n = (const float*)d_in[8];
  const float* Wfc = (const float*)d_in[9];
  float* out = (float*)d_out;

  float* ws = (float*)d_ws;
  float* wa0s   = ws;                    // [4][128]
  float* wa0n   = wa0s + 512;            // [4][128]
  float* wa1s   = wa0n + 512;            // [4][512]
  float* wa1n   = wa1s + 2048;           // [4][512]
  float* va1s   = wa1n + 2048;           // [4][4][128]
  float* va1n   = va1s + 2048;           // [4][4][128]
  float* T      = va1n + 2048;           // [4][512][256] = 524288
  float* Wfinal = T + 524288;            // [4][512][256] = 524288
  float* xaggA  = Wfinal + 524288;       // [11264][512]  = 5767168
  float* aggx   = xaggA + 11264 * 512;   // [1024][2048]  = 2097152
  float* Cpart  = aggx + 2097152;        // [8][1024][256]= 2097152
  // total ~11.0M floats = 44.1 MB

  // P1: wa vectors + T (tiled gemm)
  prepA<<<84, 256, 0, stream>>>(W0, a0s, a0n, W1, a1s, a1n, Wfc,
                                wa0s, wa0n, wa1s, wa1n, T);
  // Layer 0 attention (both levels) + Wfinal gemm + va vectors, one dispatch
  fusedB<<<11344, 256, 0, stream>>>(h0, h1, h2, wa0s, wa0n, xaggA,
                                    W0, wa1s, wa1n, T, va1s, va1n, Wfinal);
  // Layer 1 directly in xagg space
  gat_layer1<<<1024, 256, 0, stream>>>(xaggA, va1s, va1n, aggx);
  // Final: out = aggx[1024,2048] @ Wfinal[2048,256], K-split x8 + reduce
  gemm_ksplit<<<dim3(16, 2, 8), 256, 0, stream>>>(aggx, Wfinal, Cpart);
  reduce8<<<256, 256, 0, stream>>>(Cpart, out);
}